// Round 4
// baseline (896.671 us; speedup 1.0000x reference)
//
#include <hip/hip_runtime.h>
#include <math.h>

#define NNODES 50000
#define NEDGES 800000
#define MPAD   50048   // NNODES rounded up to 128

typedef __bf16 bf16_t;
typedef __attribute__((ext_vector_type(8))) __bf16 bf16x8;
typedef __attribute__((ext_vector_type(4))) float  floatx4;

__device__ __forceinline__ float bf_lo(unsigned u) { return __uint_as_float(u << 16); }
__device__ __forceinline__ float bf_hi(unsigned u) { return __uint_as_float(u & 0xffff0000u); }

// ---------------- dtype prep ----------------
__global__ void cast_x_kernel(const float* __restrict__ x, bf16_t* __restrict__ xb) {
    int i = blockIdx.x * blockDim.x + threadIdx.x;   // over MPAD*128
    if (i >= MPAD * 128) return;
    int row = i >> 7;
    xb[i] = (row < NNODES) ? (bf16_t)x[i] : (bf16_t)0.f;
}

struct W4 { const float* W[4]; };

// Wt1: [1024][128]  (global col c -> mat=c>>8, n=c&255; Wt[c][k] = W[mat][k*256+n])
__global__ void transpose_w1_kernel(W4 w, bf16_t* __restrict__ wt) {
    int i = blockIdx.x * blockDim.x + threadIdx.x;   // 1024*128
    if (i >= 1024 * 128) return;
    int c = i >> 7, k = i & 127;
    int mat = c >> 8, n = c & 255;
    wt[i] = (bf16_t)w.W[mat][(size_t)k * 256 + n];
}

// Wt2: [512][256]
__global__ void transpose_w2_kernel(W4 w, bf16_t* __restrict__ wt) {
    int i = blockIdx.x * blockDim.x + threadIdx.x;   // 512*256
    if (i >= 512 * 256) return;
    int c = i >> 8, k = i & 255;
    int mat = c >> 7, n = c & 127;
    wt[i] = (bf16_t)w.W[mat][(size_t)k * 128 + n];
}

// ---------------- CSR build ----------------
__global__ void count_deg_kernel(const int* __restrict__ dst, int* __restrict__ deg) {
    int e = blockIdx.x * blockDim.x + threadIdx.x;
    if (e < NEDGES) atomicAdd(&deg[dst[e]], 1);
}

__global__ void scan_kernel(const int* __restrict__ deg, int* __restrict__ row_ptr) {
    __shared__ int part[1024];
    const int C = (NNODES + 1023) / 1024;  // 49
    int t = threadIdx.x;
    int beg = t * C;
    int s = 0;
    for (int i = 0; i < C; i++) {
        int idx = beg + i;
        if (idx < NNODES) s += deg[idx];
    }
    part[t] = s;
    __syncthreads();
    for (int off = 1; off < 1024; off <<= 1) {
        int val = (t >= off) ? part[t - off] : 0;
        __syncthreads();
        part[t] += val;
        __syncthreads();
    }
    int run = (t == 0) ? 0 : part[t - 1];
    for (int i = 0; i < C; i++) {
        int idx = beg + i;
        if (idx < NNODES) { row_ptr[idx] = run; run += deg[idx]; }
    }
    if (t == 1023) row_ptr[NNODES] = run;
}

__global__ void scatter_kernel(const int* __restrict__ src, const int* __restrict__ dst,
                               const int* __restrict__ row_ptr, int* __restrict__ cursor,
                               int* __restrict__ esrc, int* __restrict__ edst) {
    int e = blockIdx.x * blockDim.x + threadIdx.x;
    if (e >= NEDGES) return;
    int d = dst[e];
    int slot = row_ptr[d] + atomicAdd(&cursor[d], 1);
    esrc[slot] = src[e];
    edst[slot] = d;
}

// ---------------- bf16 MFMA GEMM: C_mat = A @ W_mat + b_mat ----------------
struct GemmOut {
    const float* bias[4];
    bf16_t*      out_bf[4];   // null -> use out_f
    float*       out_f[4];
};

template <int K, int NC>
__global__ __launch_bounds__(256) void gemm_mfma_kernel(const bf16_t* __restrict__ A,
                                                        const bf16_t* __restrict__ Wt,
                                                        GemmOut args) {
    __shared__ bf16_t As[128][72];   // BK=64, row stride 144 B (16B-aligned)
    __shared__ bf16_t Bs[128][72];

    int t    = threadIdx.x;
    int lane = t & 63;
    int w    = t >> 6;
    int wm   = w >> 1, wn = w & 1;
    int tile_r = blockIdx.x * 128;
    int tile_c = blockIdx.y * 128;
    int mat = tile_c / NC;
    int tcl = tile_c % NC;

    floatx4 acc[4][4] = {};

    for (int kk = 0; kk < K; kk += 64) {
        #pragma unroll
        for (int i = 0; i < 4; i++) {
            int lin = t + i * 256;           // 0..1023
            int row = lin >> 3;              // 0..127
            int kq  = (lin & 7) * 8;         // 0..56
            *(int4*)&As[row][kq] = *(const int4*)&A[(size_t)(tile_r + row) * K + kk + kq];
            *(int4*)&Bs[row][kq] = *(const int4*)&Wt[(size_t)(tile_c + row) * K + kk + kq];
        }
        __syncthreads();
        #pragma unroll
        for (int kh = 0; kh < 64; kh += 32) {
            bf16x8 af[4], bfr[4];
            int kq = kh + (lane >> 4) * 8;
            #pragma unroll
            for (int mi = 0; mi < 4; mi++)
                af[mi] = *(const bf16x8*)&As[wm * 64 + mi * 16 + (lane & 15)][kq];
            #pragma unroll
            for (int ni = 0; ni < 4; ni++)
                bfr[ni] = *(const bf16x8*)&Bs[wn * 64 + ni * 16 + (lane & 15)][kq];
            #pragma unroll
            for (int mi = 0; mi < 4; mi++)
                #pragma unroll
                for (int ni = 0; ni < 4; ni++)
                    acc[mi][ni] = __builtin_amdgcn_mfma_f32_16x16x32_bf16(af[mi], bfr[ni], acc[mi][ni], 0, 0, 0);
        }
        __syncthreads();
    }

    // epilogue: C/D layout col=lane&15, row=(lane>>4)*4+reg
    const float* bias = args.bias[mat];
    bf16_t* obf = args.out_bf[mat];
    float*  of  = args.out_f[mat];
    float bv[4];
    #pragma unroll
    for (int ni = 0; ni < 4; ni++) bv[ni] = bias[tcl + wn * 64 + ni * 16 + (lane & 15)];
    #pragma unroll
    for (int mi = 0; mi < 4; mi++) {
        int r0 = tile_r + wm * 64 + mi * 16 + (lane >> 4) * 4;
        #pragma unroll
        for (int r = 0; r < 4; r++) {
            int gr = r0 + r;
            if (gr >= NNODES) continue;
            #pragma unroll
            for (int ni = 0; ni < 4; ni++) {
                int oc = tcl + wn * 64 + ni * 16 + (lane & 15);
                float val = acc[mi][ni][r] + bv[ni];
                if (obf) obf[(size_t)gr * NC + oc] = (bf16_t)val;
                else     of [(size_t)gr * NC + oc] = val;
            }
        }
    }
}

// ======== attention layer 1 (heads=4, d=64): 3-phase ========
// Phase A: one wave per CSR edge slot; lane = h*16+sub covers 4 dims.
__global__ void logits1_kernel(const bf16_t* __restrict__ q, const bf16_t* __restrict__ k,
                               const int* __restrict__ esrc, const int* __restrict__ edst,
                               float* __restrict__ lb) {
    int i = blockIdx.x * 4 + (threadIdx.x >> 6);
    int lane = threadIdx.x & 63;
    int off = lane * 4;
    int s = esrc[i], d = edst[i];
    uint2 qu = *(const uint2*)(q + (size_t)d * 256 + off);
    uint2 ku = *(const uint2*)(k + (size_t)s * 256 + off);
    float p = bf_lo(qu.x) * bf_lo(ku.x) + bf_hi(qu.x) * bf_hi(ku.x)
            + bf_lo(qu.y) * bf_lo(ku.y) + bf_hi(qu.y) * bf_hi(ku.y);
    p += __shfl_xor(p, 1, 64);
    p += __shfl_xor(p, 2, 64);
    p += __shfl_xor(p, 4, 64);
    p += __shfl_xor(p, 8, 64);
    if ((lane & 15) == 0) lb[(size_t)i * 4 + (lane >> 4)] = p * 0.125f;
}

// Phase B: one wave per node; lanes span edges (16 per head group). In-place alpha.
__global__ void softmax1_kernel(const int* __restrict__ row_ptr, float* __restrict__ lb) {
    int n = blockIdx.x * 4 + (threadIdx.x >> 6);
    int lane = threadIdx.x & 63;
    int h = lane >> 4, sub = lane & 15;
    int beg = row_ptr[n], deg = row_ptr[n + 1] - beg;

    float m = -INFINITY;
    for (int j = sub; j < deg; j += 16) m = fmaxf(m, lb[(size_t)(beg + j) * 4 + h]);
    m = fmaxf(m, __shfl_xor(m, 1, 64));
    m = fmaxf(m, __shfl_xor(m, 2, 64));
    m = fmaxf(m, __shfl_xor(m, 4, 64));
    m = fmaxf(m, __shfl_xor(m, 8, 64));

    float ssum = 0.f;
    for (int j = sub; j < deg; j += 16) ssum += __expf(lb[(size_t)(beg + j) * 4 + h] - m);
    ssum += __shfl_xor(ssum, 1, 64);
    ssum += __shfl_xor(ssum, 2, 64);
    ssum += __shfl_xor(ssum, 4, 64);
    ssum += __shfl_xor(ssum, 8, 64);
    float inv = 1.f / ssum;

    for (int j = sub; j < deg; j += 16) {
        size_t idx = (size_t)(beg + j) * 4 + h;
        lb[idx] = __expf(lb[idx] - m) * inv;
    }
}

// Phase C: one wave per node; inner loop = prefetched alpha*v FMA only.
__global__ void agg1_kernel(const bf16_t* __restrict__ v, const float* __restrict__ alpha,
                            const float* __restrict__ skip, const int* __restrict__ row_ptr,
                            const int* __restrict__ esrc, bf16_t* __restrict__ hout) {
    int n = blockIdx.x * 4 + (threadIdx.x >> 6);
    int lane = threadIdx.x & 63;
    int off = lane * 4;
    int h = lane >> 4;
    int beg = row_ptr[n], end = row_ptr[n + 1];

    float a0 = 0.f, a1 = 0.f, a2 = 0.f, a3 = 0.f;

    int s_cur = (beg < end) ? esrc[beg] : 0;
    uint2 vu = (beg < end) ? *(const uint2*)(v + (size_t)s_cur * 256 + off) : make_uint2(0, 0);
    float al = (beg < end) ? alpha[(size_t)beg * 4 + h] : 0.f;

    for (int i = beg; i < end; i++) {
        int s_nxt = (i + 1 < end) ? esrc[i + 1] : 0;
        uint2 vn = *(const uint2*)(v + (size_t)s_nxt * 256 + off);
        float an = (i + 1 < end) ? alpha[(size_t)(i + 1) * 4 + h] : 0.f;
        a0 += al * bf_lo(vu.x);
        a1 += al * bf_hi(vu.x);
        a2 += al * bf_lo(vu.y);
        a3 += al * bf_hi(vu.y);
        vu = vn; al = an;
    }
    size_t o = (size_t)n * 256 + off;
    float4 sk = *(const float4*)(skip + o);
    bf16_t r[4];
    r[0] = (bf16_t)fmaxf(sk.x + a0, 0.f);
    r[1] = (bf16_t)fmaxf(sk.y + a1, 0.f);
    r[2] = (bf16_t)fmaxf(sk.z + a2, 0.f);
    r[3] = (bf16_t)fmaxf(sk.w + a3, 0.f);
    *(uint2*)(hout + o) = *(uint2*)r;
}

// ======== attention layer 2 (heads=1, d=128): 3-phase ========
__global__ void logits2_kernel(const bf16_t* __restrict__ q, const bf16_t* __restrict__ k,
                               const int* __restrict__ esrc, const int* __restrict__ edst,
                               float* __restrict__ lb) {
    int i = blockIdx.x * 4 + (threadIdx.x >> 6);
    int lane = threadIdx.x & 63;
    int off = lane * 2;
    int s = esrc[i], d = edst[i];
    unsigned qu = *(const unsigned*)(q + (size_t)d * 128 + off);
    unsigned ku = *(const unsigned*)(k + (size_t)s * 128 + off);
    float p = bf_lo(qu) * bf_lo(ku) + bf_hi(qu) * bf_hi(ku);
    #pragma unroll
    for (int o = 32; o; o >>= 1) p += __shfl_xor(p, o, 64);
    if (lane == 0) lb[i] = p * 0.08838834764831845f;
}

__global__ void softmax2_kernel(const int* __restrict__ row_ptr, float* __restrict__ lb) {
    int n = blockIdx.x * 4 + (threadIdx.x >> 6);
    int lane = threadIdx.x & 63;
    int beg = row_ptr[n], deg = row_ptr[n + 1] - beg;

    float m = -INFINITY;
    for (int j = lane; j < deg; j += 64) m = fmaxf(m, lb[beg + j]);
    #pragma unroll
    for (int o = 32; o; o >>= 1) m = fmaxf(m, __shfl_xor(m, o, 64));

    float ssum = 0.f;
    for (int j = lane; j < deg; j += 64) ssum += __expf(lb[beg + j] - m);
    #pragma unroll
    for (int o = 32; o; o >>= 1) ssum += __shfl_xor(ssum, o, 64);
    float inv = 1.f / ssum;

    for (int j = lane; j < deg; j += 64) lb[beg + j] = __expf(lb[beg + j] - m) * inv;
}

__global__ void agg2_kernel(const bf16_t* __restrict__ v, const float* __restrict__ alpha,
                            const int* __restrict__ row_ptr, const int* __restrict__ esrc,
                            float* __restrict__ h2) {
    int n = blockIdx.x * 4 + (threadIdx.x >> 6);
    int lane = threadIdx.x & 63;
    int off = lane * 2;
    int beg = row_ptr[n], end = row_ptr[n + 1];

    float a0 = 0.f, a1 = 0.f;

    int s_cur = (beg < end) ? esrc[beg] : 0;
    unsigned vu = (beg < end) ? *(const unsigned*)(v + (size_t)s_cur * 128 + off) : 0u;
    float al = (beg < end) ? alpha[beg] : 0.f;

    for (int i = beg; i < end; i++) {
        int s_nxt = (i + 1 < end) ? esrc[i + 1] : 0;
        unsigned vn = *(const unsigned*)(v + (size_t)s_nxt * 128 + off);
        float an = (i + 1 < end) ? alpha[i + 1] : 0.f;
        a0 += al * bf_lo(vu);
        a1 += al * bf_hi(vu);
        vu = vn; al = an;
    }
    float2* p2 = (float2*)(h2 + (size_t)n * 128 + off);
    float2 cur = *p2;
    cur.x += a0;
    cur.y += a1;
    *p2 = cur;
}

// ---------------- final column mean over nodes ----------------
__global__ void colmean_kernel(const float* __restrict__ h2, float* __restrict__ out) {
    int t = threadIdx.x;   // 256
    int c = t & 127;
    int half = t >> 7;
    float s = 0.f;
    for (int n = blockIdx.x * 2 + half; n < NNODES; n += gridDim.x * 2)
        s += h2[(size_t)n * 128 + c];
    __shared__ float red[256];
    red[t] = s;
    __syncthreads();
    if (half == 0) {
        float tot = red[c] + red[c + 128];
        atomicAdd(&out[c], tot * (1.0f / NNODES));
    }
}

extern "C" void kernel_launch(void* const* d_in, const int* in_sizes, int n_in,
                              void* d_out, int out_size, void* d_ws, size_t ws_size,
                              hipStream_t stream) {
    const float* x  = (const float*)d_in[0];
    const int*   ei = (const int*)d_in[1];   // int32: [2, E]
    const int* src = ei;
    const int* dst = ei + NEDGES;

    const float* Wq1 = (const float*)d_in[2];  const float* bq1 = (const float*)d_in[3];
    const float* Wk1 = (const float*)d_in[4];  const float* bk1 = (const float*)d_in[5];
    const float* Wv1 = (const float*)d_in[6];  const float* bv1 = (const float*)d_in[7];
    const float* Ws1 = (const float*)d_in[8];  const float* bs1 = (const float*)d_in[9];
    const float* Wq2 = (const float*)d_in[10]; const float* bq2 = (const float*)d_in[11];
    const float* Wk2 = (const float*)d_in[12]; const float* bk2 = (const float*)d_in[13];
    const float* Wv2 = (const float*)d_in[14]; const float* bv2 = (const float*)d_in[15];
    const float* Ws2 = (const float*)d_in[16]; const float* bs2 = (const float*)d_in[17];

    float* out = (float*)d_out;

    // ---- workspace layout (byte offsets, all 16B-aligned) ----
    char* ws = (char*)d_ws;
    bf16_t* qkv1  = (bf16_t*)(ws);                 // 3*N*256 bf16 = 76,800,000 B
    bf16_t* q1 = qkv1;
    bf16_t* k1 = qkv1 + (size_t)NNODES * 256;
    bf16_t* v1 = qkv1 + (size_t)2 * NNODES * 256;
    float*  hskip = (float*)(ws + 76800000);       // N*256 f32 = 51,200,000 B
    bf16_t* hbf   = (bf16_t*)(ws + 128000000);     // MPAD*256 bf16 = 25,624,576 B
    bf16_t* xbf   = (bf16_t*)(ws + 153624576);     // MPAD*128 bf16 = 12,812,288 B
    bf16_t* wt1   = (bf16_t*)(ws + 166436864);     // 1024*128 bf16 = 262,144 B
    bf16_t* wt2   = (bf16_t*)(ws + 166699008);     // 512*256 bf16  = 262,144 B
    int* deg     = (int*)(ws + 166961152);         // N
    int* row_ptr = deg + NNODES;                   // N+1
    int* cursor  = row_ptr + NNODES + 1;           // N
    int* esrc    = cursor + NNODES;                // E
    int* edst    = esrc + NEDGES;                  // E  (ends at ~173.96 MB)
    // aliases (stream-ordered lifetimes):
    float* lb1 = (float*)xbf;                      // E*4 f32 = 12.8 MB; xbf dead after gemm1
    // layer-2 buffers alias dead qkv1 region
    bf16_t* qkv2 = (bf16_t*)(ws);                  // 3*N*128 bf16 = 38,400,000 B
    bf16_t* q2 = qkv2;
    bf16_t* k2 = qkv2 + (size_t)NNODES * 128;
    bf16_t* v2 = qkv2 + (size_t)2 * NNODES * 128;
    float*  h2 = (float*)(ws + 38400000);          // N*128 f32 = 25,600,000 B
    float*  lb2 = (float*)hskip;                   // E f32 = 3.2 MB; hskip dead after agg1

    hipMemsetAsync(deg, 0, sizeof(int) * NNODES, stream);
    hipMemsetAsync(cursor, 0, sizeof(int) * NNODES, stream);
    hipMemsetAsync(out, 0, sizeof(float) * 128, stream);
    hipMemsetAsync(hbf + (size_t)NNODES * 256, 0, (size_t)(MPAD - NNODES) * 256 * sizeof(bf16_t), stream);

    // dtype prep
    cast_x_kernel<<<(MPAD * 128 + 255) / 256, 256, 0, stream>>>(x, xbf);
    W4 w1; w1.W[0] = Wq1; w1.W[1] = Wk1; w1.W[2] = Wv1; w1.W[3] = Ws1;
    transpose_w1_kernel<<<(1024 * 128 + 255) / 256, 256, 0, stream>>>(w1, wt1);
    W4 w2; w2.W[0] = Wq2; w2.W[1] = Wk2; w2.W[2] = Wv2; w2.W[3] = Ws2;
    transpose_w2_kernel<<<(512 * 256 + 255) / 256, 256, 0, stream>>>(w2, wt2);

    // CSR
    int blocksE = (NEDGES + 255) / 256;
    count_deg_kernel<<<blocksE, 256, 0, stream>>>(dst, deg);
    scan_kernel<<<1, 1024, 0, stream>>>(deg, row_ptr);
    scatter_kernel<<<blocksE, 256, 0, stream>>>(src, dst, row_ptr, cursor, esrc, edst);

    // layer 1
    GemmOut a1;
    a1.bias[0] = bq1; a1.bias[1] = bk1; a1.bias[2] = bv1; a1.bias[3] = bs1;
    a1.out_bf[0] = q1; a1.out_bf[1] = k1; a1.out_bf[2] = v1; a1.out_bf[3] = nullptr;
    a1.out_f[0] = nullptr; a1.out_f[1] = nullptr; a1.out_f[2] = nullptr; a1.out_f[3] = hskip;
    dim3 g1(MPAD / 128, 1024 / 128);   // 391 x 8
    gemm_mfma_kernel<128, 256><<<g1, 256, 0, stream>>>(xbf, wt1, a1);

    logits1_kernel<<<NEDGES / 4, 256, 0, stream>>>(q1, k1, esrc, edst, lb1);
    softmax1_kernel<<<NNODES / 4, 256, 0, stream>>>(row_ptr, lb1);
    agg1_kernel<<<NNODES / 4, 256, 0, stream>>>(v1, lb1, hskip, row_ptr, esrc, hbf);

    // layer 2
    GemmOut a2;
    a2.bias[0] = bq2; a2.bias[1] = bk2; a2.bias[2] = bv2; a2.bias[3] = bs2;
    a2.out_bf[0] = q2; a2.out_bf[1] = k2; a2.out_bf[2] = v2; a2.out_bf[3] = nullptr;
    a2.out_f[0] = nullptr; a2.out_f[1] = nullptr; a2.out_f[2] = nullptr; a2.out_f[3] = h2;
    dim3 g2(MPAD / 128, 512 / 128);    // 391 x 4
    gemm_mfma_kernel<256, 128><<<g2, 256, 0, stream>>>(hbf, wt2, a2);

    logits2_kernel<<<NEDGES / 4, 256, 0, stream>>>(q2, k2, esrc, edst, lb2);
    softmax2_kernel<<<NNODES / 4, 256, 0, stream>>>(row_ptr, lb2);
    agg2_kernel<<<NNODES / 4, 256, 0, stream>>>(v2, lb2, row_ptr, esrc, h2);

    colmean_kernel<<<256, 256, 0, stream>>>(h2, out);
}

// Round 5
// 625.499 us; speedup vs baseline: 1.4335x; 1.4335x over previous
//
#include <hip/hip_runtime.h>
#include <math.h>

#define NNODES 50000
#define NEDGES 800000
#define MPAD   50048   // NNODES rounded up to 128

typedef __bf16 bf16_t;
typedef __attribute__((ext_vector_type(8))) __bf16 bf16x8;
typedef __attribute__((ext_vector_type(4))) float  floatx4;

__device__ __forceinline__ float bf_lo(unsigned u) { return __uint_as_float(u << 16); }
__device__ __forceinline__ float bf_hi(unsigned u) { return __uint_as_float(u & 0xffff0000u); }

// ---------------- dtype prep ----------------
__global__ void cast_x_kernel(const float* __restrict__ x, bf16_t* __restrict__ xb) {
    int i = blockIdx.x * blockDim.x + threadIdx.x;   // over MPAD*128
    if (i >= MPAD * 128) return;
    int row = i >> 7;
    xb[i] = (row < NNODES) ? (bf16_t)x[i] : (bf16_t)0.f;
}

struct W4 { const float* W[4]; };

// Wt1: [1024][128]  (global col c -> mat=c>>8, n=c&255; Wt[c][k] = W[mat][k*256+n])
__global__ void transpose_w1_kernel(W4 w, bf16_t* __restrict__ wt) {
    int i = blockIdx.x * blockDim.x + threadIdx.x;   // 1024*128
    if (i >= 1024 * 128) return;
    int c = i >> 7, k = i & 127;
    int mat = c >> 8, n = c & 255;
    wt[i] = (bf16_t)w.W[mat][(size_t)k * 256 + n];
}

// Wt2: [512][256]
__global__ void transpose_w2_kernel(W4 w, bf16_t* __restrict__ wt) {
    int i = blockIdx.x * blockDim.x + threadIdx.x;   // 512*256
    if (i >= 512 * 256) return;
    int c = i >> 8, k = i & 255;
    int mat = c >> 7, n = c & 127;
    wt[i] = (bf16_t)w.W[mat][(size_t)k * 128 + n];
}

// ---------------- CSR build ----------------
__global__ void count_deg_kernel(const int* __restrict__ dst, int* __restrict__ deg) {
    int e = blockIdx.x * blockDim.x + threadIdx.x;
    if (e < NEDGES) atomicAdd(&deg[dst[e]], 1);
}

__global__ void scan_kernel(const int* __restrict__ deg, int* __restrict__ row_ptr) {
    __shared__ int part[1024];
    const int C = (NNODES + 1023) / 1024;  // 49
    int t = threadIdx.x;
    int beg = t * C;
    int s = 0;
    for (int i = 0; i < C; i++) {
        int idx = beg + i;
        if (idx < NNODES) s += deg[idx];
    }
    part[t] = s;
    __syncthreads();
    for (int off = 1; off < 1024; off <<= 1) {
        int val = (t >= off) ? part[t - off] : 0;
        __syncthreads();
        part[t] += val;
        __syncthreads();
    }
    int run = (t == 0) ? 0 : part[t - 1];
    for (int i = 0; i < C; i++) {
        int idx = beg + i;
        if (idx < NNODES) { row_ptr[idx] = run; run += deg[idx]; }
    }
    if (t == 1023) row_ptr[NNODES] = run;
}

__global__ void scatter_kernel(const int* __restrict__ src, const int* __restrict__ dst,
                               const int* __restrict__ row_ptr, int* __restrict__ cursor,
                               int* __restrict__ esrc) {
    int e = blockIdx.x * blockDim.x + threadIdx.x;
    if (e >= NEDGES) return;
    int d = dst[e];
    int slot = row_ptr[d] + atomicAdd(&cursor[d], 1);
    esrc[slot] = src[e];
}

// ---------------- bf16 MFMA GEMM: C_mat = A @ W_mat + b_mat ----------------
struct GemmOut {
    const float* bias[4];
    bf16_t*      out_bf[4];   // null -> use out_f
    float*       out_f[4];
};

template <int K, int NC>
__global__ __launch_bounds__(256) void gemm_mfma_kernel(const bf16_t* __restrict__ A,
                                                        const bf16_t* __restrict__ Wt,
                                                        GemmOut args) {
    __shared__ bf16_t As[128][72];   // BK=64, row stride 144 B (16B-aligned)
    __shared__ bf16_t Bs[128][72];

    int t    = threadIdx.x;
    int lane = t & 63;
    int w    = t >> 6;
    int wm   = w >> 1, wn = w & 1;
    int tile_r = blockIdx.x * 128;
    int tile_c = blockIdx.y * 128;
    int mat = tile_c / NC;
    int tcl = tile_c % NC;

    floatx4 acc[4][4] = {};

    for (int kk = 0; kk < K; kk += 64) {
        #pragma unroll
        for (int i = 0; i < 4; i++) {
            int lin = t + i * 256;           // 0..1023
            int row = lin >> 3;              // 0..127
            int kq  = (lin & 7) * 8;         // 0..56
            *(int4*)&As[row][kq] = *(const int4*)&A[(size_t)(tile_r + row) * K + kk + kq];
            *(int4*)&Bs[row][kq] = *(const int4*)&Wt[(size_t)(tile_c + row) * K + kk + kq];
        }
        __syncthreads();
        #pragma unroll
        for (int kh = 0; kh < 64; kh += 32) {
            bf16x8 af[4], bfr[4];
            int kq = kh + (lane >> 4) * 8;
            #pragma unroll
            for (int mi = 0; mi < 4; mi++)
                af[mi] = *(const bf16x8*)&As[wm * 64 + mi * 16 + (lane & 15)][kq];
            #pragma unroll
            for (int ni = 0; ni < 4; ni++)
                bfr[ni] = *(const bf16x8*)&Bs[wn * 64 + ni * 16 + (lane & 15)][kq];
            #pragma unroll
            for (int mi = 0; mi < 4; mi++)
                #pragma unroll
                for (int ni = 0; ni < 4; ni++)
                    acc[mi][ni] = __builtin_amdgcn_mfma_f32_16x16x32_bf16(af[mi], bfr[ni], acc[mi][ni], 0, 0, 0);
        }
        __syncthreads();
    }

    // epilogue: C/D layout col=lane&15, row=(lane>>4)*4+reg
    const float* bias = args.bias[mat];
    bf16_t* obf = args.out_bf[mat];
    float*  of  = args.out_f[mat];
    float bv[4];
    #pragma unroll
    for (int ni = 0; ni < 4; ni++) bv[ni] = bias[tcl + wn * 64 + ni * 16 + (lane & 15)];
    #pragma unroll
    for (int mi = 0; mi < 4; mi++) {
        int r0 = tile_r + wm * 64 + mi * 16 + (lane >> 4) * 4;
        #pragma unroll
        for (int r = 0; r < 4; r++) {
            int gr = r0 + r;
            if (gr >= NNODES) continue;
            #pragma unroll
            for (int ni = 0; ni < 4; ni++) {
                int oc = tcl + wn * 64 + ni * 16 + (lane & 15);
                float val = acc[mi][ni][r] + bv[ni];
                if (obf) obf[(size_t)gr * NC + oc] = (bf16_t)val;
                else     of [(size_t)gr * NC + oc] = val;
            }
        }
    }
}

// ---- attention layer 1 (heads=4, d=64): ONE BLOCK (4 waves) PER NODE ----
// Each wave processes a strided quarter of the node's edges with online softmax;
// partial (m,l,acc) states merge once via LDS. lane covers 4 dims; head=lane>>4.
__global__ void attn1_kernel(const bf16_t* __restrict__ q, const bf16_t* __restrict__ k,
                             const bf16_t* __restrict__ v, const float* __restrict__ skip,
                             const int* __restrict__ row_ptr, const int* __restrict__ esrc,
                             bf16_t* __restrict__ hout) {
    int n = blockIdx.x;
    int t = threadIdx.x;
    int g = t >> 6;          // wave 0..3
    int lane = t & 63;
    int off = lane * 4;
    int h = lane >> 4;

    int beg = row_ptr[n], end = row_ptr[n + 1];

    uint2 qu = *(const uint2*)(q + (size_t)n * 256 + off);
    float q0 = bf_lo(qu.x), q1 = bf_hi(qu.x), q2 = bf_lo(qu.y), q3 = bf_hi(qu.y);

    float m = -INFINITY, l = 0.f;
    float a0 = 0.f, a1 = 0.f, a2 = 0.f, a3 = 0.f;

    int i0 = beg + g;
    int s_cur = (i0 < end) ? esrc[i0] : 0;
    uint2 ku = (i0 < end) ? *(const uint2*)(k + (size_t)s_cur * 256 + off) : make_uint2(0, 0);
    uint2 vu = (i0 < end) ? *(const uint2*)(v + (size_t)s_cur * 256 + off) : make_uint2(0, 0);

    for (int i = i0; i < end; i += 4) {
        int s_nxt = (i + 4 < end) ? esrc[i + 4] : 0;
        uint2 kn = *(const uint2*)(k + (size_t)s_nxt * 256 + off);
        uint2 vn = *(const uint2*)(v + (size_t)s_nxt * 256 + off);

        float p = q0 * bf_lo(ku.x) + q1 * bf_hi(ku.x) + q2 * bf_lo(ku.y) + q3 * bf_hi(ku.y);
        p += __shfl_xor(p, 1, 64);
        p += __shfl_xor(p, 2, 64);
        p += __shfl_xor(p, 4, 64);
        p += __shfl_xor(p, 8, 64);
        float logit = p * 0.125f;  // 1/sqrt(64)
        float nm = fmaxf(m, logit);
        float f  = __expf(m - nm);
        float pe = __expf(logit - nm);
        l = l * f + pe;
        a0 = a0 * f + pe * bf_lo(vu.x);
        a1 = a1 * f + pe * bf_hi(vu.x);
        a2 = a2 * f + pe * bf_lo(vu.y);
        a3 = a3 * f + pe * bf_hi(vu.y);
        m = nm;
        ku = kn; vu = vn;
    }

    // merge 4 partial states
    __shared__ float sm_m[4][4], sm_l[4][4];
    __shared__ float sacc[4][64][4];
    if ((lane & 15) == 0) { sm_m[g][h] = m; sm_l[g][h] = l; }
    sacc[g][lane][0] = a0; sacc[g][lane][1] = a1;
    sacc[g][lane][2] = a2; sacc[g][lane][3] = a3;
    __syncthreads();
    if (g == 0) {
        float mstar = fmaxf(fmaxf(sm_m[0][h], sm_m[1][h]), fmaxf(sm_m[2][h], sm_m[3][h]));
        float lstar = 0.f, c0 = 0.f, c1 = 0.f, c2 = 0.f, c3 = 0.f;
        #pragma unroll
        for (int gg = 0; gg < 4; gg++) {
            float lg = sm_l[gg][h];
            float sc = (lg > 0.f) ? __expf(sm_m[gg][h] - mstar) : 0.f;
            lstar += lg * sc;
            c0 += sc * sacc[gg][lane][0];
            c1 += sc * sacc[gg][lane][1];
            c2 += sc * sacc[gg][lane][2];
            c3 += sc * sacc[gg][lane][3];
        }
        float inv = (lstar > 0.f) ? 1.f / lstar : 0.f;
        size_t o = (size_t)n * 256 + off;
        float4 sk = *(const float4*)(skip + o);
        bf16_t r[4];
        r[0] = (bf16_t)fmaxf(sk.x + c0 * inv, 0.f);
        r[1] = (bf16_t)fmaxf(sk.y + c1 * inv, 0.f);
        r[2] = (bf16_t)fmaxf(sk.z + c2 * inv, 0.f);
        r[3] = (bf16_t)fmaxf(sk.w + c3 * inv, 0.f);
        *(uint2*)(hout + o) = *(uint2*)r;
    }
}

// ---- attention layer 2 (heads=1, d=128): ONE BLOCK (4 waves) PER NODE ----
// lane covers 2 dims.
__global__ void attn2_kernel(const bf16_t* __restrict__ q, const bf16_t* __restrict__ k,
                             const bf16_t* __restrict__ v, const int* __restrict__ row_ptr,
                             const int* __restrict__ esrc, float* __restrict__ h2) {
    int n = blockIdx.x;
    int t = threadIdx.x;
    int g = t >> 6;
    int lane = t & 63;
    int off = lane * 2;

    int beg = row_ptr[n], end = row_ptr[n + 1];

    unsigned qu = *(const unsigned*)(q + (size_t)n * 128 + off);
    float q0 = bf_lo(qu), q1 = bf_hi(qu);

    float m = -INFINITY, l = 0.f, a0 = 0.f, a1 = 0.f;

    int i0 = beg + g;
    int s_cur = (i0 < end) ? esrc[i0] : 0;
    unsigned ku = (i0 < end) ? *(const unsigned*)(k + (size_t)s_cur * 128 + off) : 0u;
    unsigned vu = (i0 < end) ? *(const unsigned*)(v + (size_t)s_cur * 128 + off) : 0u;

    for (int i = i0; i < end; i += 4) {
        int s_nxt = (i + 4 < end) ? esrc[i + 4] : 0;
        unsigned kn = *(const unsigned*)(k + (size_t)s_nxt * 128 + off);
        unsigned vn = *(const unsigned*)(v + (size_t)s_nxt * 128 + off);

        float p = q0 * bf_lo(ku) + q1 * bf_hi(ku);
        #pragma unroll
        for (int o = 32; o; o >>= 1) p += __shfl_xor(p, o, 64);
        float logit = p * 0.08838834764831845f;  // 1/sqrt(128)
        float nm = fmaxf(m, logit);
        float f  = __expf(m - nm);
        float pe = __expf(logit - nm);
        l  = l * f + pe;
        a0 = a0 * f + pe * bf_lo(vu);
        a1 = a1 * f + pe * bf_hi(vu);
        m = nm;
        ku = kn; vu = vn;
    }

    __shared__ float sm_m[4], sm_l[4];
    __shared__ float sacc[4][64][2];
    if (lane == 0) { sm_m[g] = m; sm_l[g] = l; }
    sacc[g][lane][0] = a0; sacc[g][lane][1] = a1;
    __syncthreads();
    if (g == 0) {
        float mstar = fmaxf(fmaxf(sm_m[0], sm_m[1]), fmaxf(sm_m[2], sm_m[3]));
        float lstar = 0.f, c0 = 0.f, c1 = 0.f;
        #pragma unroll
        for (int gg = 0; gg < 4; gg++) {
            float lg = sm_l[gg];
            float sc = (lg > 0.f) ? __expf(sm_m[gg] - mstar) : 0.f;
            lstar += lg * sc;
            c0 += sc * sacc[gg][lane][0];
            c1 += sc * sacc[gg][lane][1];
        }
        float inv = (lstar > 0.f) ? 1.f / lstar : 0.f;
        float2* p2 = (float2*)(h2 + (size_t)n * 128 + off);
        float2 cur = *p2;
        cur.x += c0 * inv;
        cur.y += c1 * inv;
        *p2 = cur;
    }
}

// ---------------- final column mean over nodes ----------------
__global__ void colmean_kernel(const float* __restrict__ h2, float* __restrict__ out) {
    int t = threadIdx.x;   // 256
    int c = t & 127;
    int half = t >> 7;
    float s = 0.f;
    for (int n = blockIdx.x * 2 + half; n < NNODES; n += gridDim.x * 2)
        s += h2[(size_t)n * 128 + c];
    __shared__ float red[256];
    red[t] = s;
    __syncthreads();
    if (half == 0) {
        float tot = red[c] + red[c + 128];
        atomicAdd(&out[c], tot * (1.0f / NNODES));
    }
}

extern "C" void kernel_launch(void* const* d_in, const int* in_sizes, int n_in,
                              void* d_out, int out_size, void* d_ws, size_t ws_size,
                              hipStream_t stream) {
    const float* x  = (const float*)d_in[0];
    const int*   ei = (const int*)d_in[1];   // int32: [2, E]
    const int* src = ei;
    const int* dst = ei + NEDGES;

    const float* Wq1 = (const float*)d_in[2];  const float* bq1 = (const float*)d_in[3];
    const float* Wk1 = (const float*)d_in[4];  const float* bk1 = (const float*)d_in[5];
    const float* Wv1 = (const float*)d_in[6];  const float* bv1 = (const float*)d_in[7];
    const float* Ws1 = (const float*)d_in[8];  const float* bs1 = (const float*)d_in[9];
    const float* Wq2 = (const float*)d_in[10]; const float* bq2 = (const float*)d_in[11];
    const float* Wk2 = (const float*)d_in[12]; const float* bk2 = (const float*)d_in[13];
    const float* Wv2 = (const float*)d_in[14]; const float* bv2 = (const float*)d_in[15];
    const float* Ws2 = (const float*)d_in[16]; const float* bs2 = (const float*)d_in[17];

    float* out = (float*)d_out;

    // ---- workspace layout (byte offsets, all 16B-aligned) ----
    char* ws = (char*)d_ws;
    bf16_t* qkv1  = (bf16_t*)(ws);                 // 3*N*256 bf16 = 76,800,000 B
    bf16_t* q1 = qkv1;
    bf16_t* k1 = qkv1 + (size_t)NNODES * 256;
    bf16_t* v1 = qkv1 + (size_t)2 * NNODES * 256;
    float*  hskip = (float*)(ws + 76800000);       // N*256 f32 = 51,200,000 B
    bf16_t* hbf   = (bf16_t*)(ws + 128000000);     // MPAD*256 bf16 = 25,624,576 B
    bf16_t* xbf   = (bf16_t*)(ws + 153624576);     // MPAD*128 bf16 = 12,812,288 B
    bf16_t* wt1   = (bf16_t*)(ws + 166436864);     // 1024*128 bf16 = 262,144 B
    bf16_t* wt2   = (bf16_t*)(ws + 166699008);     // 512*256 bf16  = 262,144 B
    int* deg     = (int*)(ws + 166961152);         // N
    int* row_ptr = deg + NNODES;                   // N+1
    int* cursor  = row_ptr + NNODES + 1;           // N
    int* esrc    = cursor + NNODES;                // E
    // layer-2 buffers alias dead qkv1 region (stream-ordered lifetimes)
    bf16_t* qkv2 = (bf16_t*)(ws);                  // 3*N*128 bf16 = 38,400,000 B
    bf16_t* q2 = qkv2;
    bf16_t* k2 = qkv2 + (size_t)NNODES * 128;
    bf16_t* v2 = qkv2 + (size_t)2 * NNODES * 128;
    float*  h2 = (float*)(ws + 38400000);          // N*128 f32 = 25,600,000 B

    hipMemsetAsync(deg, 0, sizeof(int) * NNODES, stream);
    hipMemsetAsync(cursor, 0, sizeof(int) * NNODES, stream);
    hipMemsetAsync(out, 0, sizeof(float) * 128, stream);
    hipMemsetAsync(hbf + (size_t)NNODES * 256, 0, (size_t)(MPAD - NNODES) * 256 * sizeof(bf16_t), stream);

    // dtype prep
    cast_x_kernel<<<(MPAD * 128 + 255) / 256, 256, 0, stream>>>(x, xbf);
    W4 w1; w1.W[0] = Wq1; w1.W[1] = Wk1; w1.W[2] = Wv1; w1.W[3] = Ws1;
    transpose_w1_kernel<<<(1024 * 128 + 255) / 256, 256, 0, stream>>>(w1, wt1);
    W4 w2; w2.W[0] = Wq2; w2.W[1] = Wk2; w2.W[2] = Wv2; w2.W[3] = Ws2;
    transpose_w2_kernel<<<(512 * 256 + 255) / 256, 256, 0, stream>>>(w2, wt2);

    // CSR
    int blocksE = (NEDGES + 255) / 256;
    count_deg_kernel<<<blocksE, 256, 0, stream>>>(dst, deg);
    scan_kernel<<<1, 1024, 0, stream>>>(deg, row_ptr);
    scatter_kernel<<<blocksE, 256, 0, stream>>>(src, dst, row_ptr, cursor, esrc);

    // layer 1
    GemmOut a1;
    a1.bias[0] = bq1; a1.bias[1] = bk1; a1.bias[2] = bv1; a1.bias[3] = bs1;
    a1.out_bf[0] = q1; a1.out_bf[1] = k1; a1.out_bf[2] = v1; a1.out_bf[3] = nullptr;
    a1.out_f[0] = nullptr; a1.out_f[1] = nullptr; a1.out_f[2] = nullptr; a1.out_f[3] = hskip;
    dim3 g1(MPAD / 128, 1024 / 128);   // 391 x 8
    gemm_mfma_kernel<128, 256><<<g1, 256, 0, stream>>>(xbf, wt1, a1);

    attn1_kernel<<<NNODES, 256, 0, stream>>>(q1, k1, v1, hskip, row_ptr, esrc, hbf);

    // layer 2
    GemmOut a2;
    a2.bias[0] = bq2; a2.bias[1] = bk2; a2.bias[2] = bv2; a2.bias[3] = bs2;
    a2.out_bf[0] = q2; a2.out_bf[1] = k2; a2.out_bf[2] = v2; a2.out_bf[3] = nullptr;
    a2.out_f[0] = nullptr; a2.out_f[1] = nullptr; a2.out_f[2] = nullptr; a2.out_f[3] = h2;
    dim3 g2(MPAD / 128, 512 / 128);    // 391 x 4
    gemm_mfma_kernel<256, 128><<<g2, 256, 0, stream>>>(hbf, wt2, a2);

    attn2_kernel<<<NNODES, 256, 0, stream>>>(q2, k2, v2, row_ptr, esrc, h2);

    colmean_kernel<<<256, 256, 0, stream>>>(h2, out);
}

// Round 6
// 611.614 us; speedup vs baseline: 1.4661x; 1.0227x over previous
//
#include <hip/hip_runtime.h>
#include <math.h>

#define NNODES 50000
#define NEDGES 800000
#define MPAD   50048   // NNODES rounded up to 128

typedef __bf16 bf16_t;
typedef unsigned char u8;
typedef __attribute__((ext_vector_type(8))) __bf16 bf16x8;
typedef __attribute__((ext_vector_type(4))) float  floatx4;
typedef __attribute__((ext_vector_type(2))) float  floatx2;

__device__ __forceinline__ float bf_lo(unsigned u) { return __uint_as_float(u << 16); }
__device__ __forceinline__ float bf_hi(unsigned u) { return __uint_as_float(u & 0xffff0000u); }

struct W4 { const float* W[4]; };

// ---------------- fused prep: cast x -> bf16 (padded), transpose W1/W2 -> bf16 ----
__global__ void prep_kernel(const float* __restrict__ x, W4 w1, W4 w2,
                            bf16_t* __restrict__ xb, bf16_t* __restrict__ wt1,
                            bf16_t* __restrict__ wt2) {
    int i = blockIdx.x * blockDim.x + threadIdx.x;
    if (i < MPAD * 128) {
        int row = i >> 7;
        xb[i] = (row < NNODES) ? (bf16_t)x[i] : (bf16_t)0.f;
    } else if (i < MPAD * 128 + 1024 * 128) {
        int j = i - MPAD * 128;
        int c = j >> 7, k = j & 127;
        wt1[j] = (bf16_t)w1.W[c >> 8][(size_t)k * 256 + (c & 255)];
    } else if (i < MPAD * 128 + 1024 * 128 + 512 * 256) {
        int j = i - MPAD * 128 - 1024 * 128;
        int c = j >> 8, k = j & 255;
        wt2[j] = (bf16_t)w2.W[c >> 7][(size_t)k * 128 + (c & 127)];
    }
}

// ---------------- CSR build ----------------
__global__ void count_deg_kernel(const int* __restrict__ dst, int* __restrict__ deg) {
    int e = blockIdx.x * blockDim.x + threadIdx.x;
    if (e < NEDGES) atomicAdd(&deg[dst[e]], 1);
}

__global__ void scan_kernel(const int* __restrict__ deg, int* __restrict__ row_ptr) {
    __shared__ int part[1024];
    const int C = (NNODES + 1023) / 1024;  // 49
    int t = threadIdx.x;
    int beg = t * C;
    int s = 0;
    for (int i = 0; i < C; i++) {
        int idx = beg + i;
        if (idx < NNODES) s += deg[idx];
    }
    part[t] = s;
    __syncthreads();
    for (int off = 1; off < 1024; off <<= 1) {
        int val = (t >= off) ? part[t - off] : 0;
        __syncthreads();
        part[t] += val;
        __syncthreads();
    }
    int run = (t == 0) ? 0 : part[t - 1];
    for (int i = 0; i < C; i++) {
        int idx = beg + i;
        if (idx < NNODES) { row_ptr[idx] = run; run += deg[idx]; }
    }
    if (t == 1023) row_ptr[NNODES] = run;
}

__global__ void scatter_kernel(const int* __restrict__ src, const int* __restrict__ dst,
                               const int* __restrict__ row_ptr, int* __restrict__ cursor,
                               int* __restrict__ esrc) {
    int e = blockIdx.x * blockDim.x + threadIdx.x;
    if (e >= NEDGES) return;
    int d = dst[e];
    int slot = row_ptr[d] + atomicAdd(&cursor[d], 1);
    esrc[slot] = src[e];
}

// ---------------- bf16 MFMA GEMM: C_mat = A @ W_mat + b_mat ----------------
// per-mat output mode: 0 = f32, 1 = bf16, 2 = fp8 e4m3
struct GemmOut {
    const float* bias[4];
    void*        out[4];
    int          mode[4];
};

template <int K, int NC>
__global__ __launch_bounds__(256) void gemm_mfma_kernel(const bf16_t* __restrict__ A,
                                                        const bf16_t* __restrict__ Wt,
                                                        GemmOut args) {
    __shared__ bf16_t As[128][72];   // BK=64, row stride 144 B (16B-aligned)
    __shared__ bf16_t Bs[128][72];

    int t    = threadIdx.x;
    int lane = t & 63;
    int w    = t >> 6;
    int wm   = w >> 1, wn = w & 1;
    int tile_r = blockIdx.x * 128;
    int tile_c = blockIdx.y * 128;
    int mat = tile_c / NC;
    int tcl = tile_c % NC;

    floatx4 acc[4][4] = {};

    for (int kk = 0; kk < K; kk += 64) {
        #pragma unroll
        for (int i = 0; i < 4; i++) {
            int lin = t + i * 256;           // 0..1023
            int row = lin >> 3;              // 0..127
            int kq  = (lin & 7) * 8;         // 0..56
            *(int4*)&As[row][kq] = *(const int4*)&A[(size_t)(tile_r + row) * K + kk + kq];
            *(int4*)&Bs[row][kq] = *(const int4*)&Wt[(size_t)(tile_c + row) * K + kk + kq];
        }
        __syncthreads();
        #pragma unroll
        for (int kh = 0; kh < 64; kh += 32) {
            bf16x8 af[4], bfr[4];
            int kq = kh + (lane >> 4) * 8;
            #pragma unroll
            for (int mi = 0; mi < 4; mi++)
                af[mi] = *(const bf16x8*)&As[wm * 64 + mi * 16 + (lane & 15)][kq];
            #pragma unroll
            for (int ni = 0; ni < 4; ni++)
                bfr[ni] = *(const bf16x8*)&Bs[wn * 64 + ni * 16 + (lane & 15)][kq];
            #pragma unroll
            for (int mi = 0; mi < 4; mi++)
                #pragma unroll
                for (int ni = 0; ni < 4; ni++)
                    acc[mi][ni] = __builtin_amdgcn_mfma_f32_16x16x32_bf16(af[mi], bfr[ni], acc[mi][ni], 0, 0, 0);
        }
        __syncthreads();
    }

    // epilogue: C/D layout col=lane&15, row=(lane>>4)*4+reg
    const float* bias = args.bias[mat];
    void* op = args.out[mat];
    int mode = args.mode[mat];
    float bv[4];
    #pragma unroll
    for (int ni = 0; ni < 4; ni++) bv[ni] = bias[tcl + wn * 64 + ni * 16 + (lane & 15)];
    #pragma unroll
    for (int mi = 0; mi < 4; mi++) {
        int r0 = tile_r + wm * 64 + mi * 16 + (lane >> 4) * 4;
        #pragma unroll
        for (int r = 0; r < 4; r++) {
            int gr = r0 + r;
            if (gr >= NNODES) continue;
            #pragma unroll
            for (int ni = 0; ni < 4; ni++) {
                int oc = tcl + wn * 64 + ni * 16 + (lane & 15);
                float val = acc[mi][ni][r] + bv[ni];
                size_t idx = (size_t)gr * NC + oc;
                if (mode == 0)      ((float*)op)[idx]  = val;
                else if (mode == 1) ((bf16_t*)op)[idx] = (bf16_t)val;
                else ((u8*)op)[idx] = (u8)(__builtin_amdgcn_cvt_pk_fp8_f32(val, val, 0, false) & 0xff);
            }
        }
    }
}

// ---- attention layer 1 (heads=4, d=64): ONE BLOCK (4 waves) PER NODE, fp8 k/v ----
__global__ void attn1_kernel(const bf16_t* __restrict__ q, const u8* __restrict__ kf,
                             const u8* __restrict__ vf, const bf16_t* __restrict__ skip,
                             const int* __restrict__ row_ptr, const int* __restrict__ esrc,
                             bf16_t* __restrict__ hout) {
    int n = blockIdx.x;
    int t = threadIdx.x;
    int g = t >> 6;          // wave 0..3
    int lane = t & 63;
    int off = lane * 4;      // dim offset within 256 (also byte offset in fp8 row)
    int h = lane >> 4;

    int beg = row_ptr[n], end = row_ptr[n + 1];

    uint2 qu = *(const uint2*)(q + (size_t)n * 256 + off);
    float q0 = bf_lo(qu.x), q1 = bf_hi(qu.x), q2 = bf_lo(qu.y), q3 = bf_hi(qu.y);

    float m = -INFINITY, l = 0.f;
    float a0 = 0.f, a1 = 0.f, a2 = 0.f, a3 = 0.f;

    int i0 = beg + g;
    int s_cur = (i0 < end) ? esrc[i0] : 0;
    unsigned ku = (i0 < end) ? *(const unsigned*)(kf + (size_t)s_cur * 256 + off) : 0u;
    unsigned vu = (i0 < end) ? *(const unsigned*)(vf + (size_t)s_cur * 256 + off) : 0u;

    for (int i = i0; i < end; i += 4) {
        int s_nxt = (i + 4 < end) ? esrc[i + 4] : 0;
        unsigned kn = *(const unsigned*)(kf + (size_t)s_nxt * 256 + off);
        unsigned vn = *(const unsigned*)(vf + (size_t)s_nxt * 256 + off);

        floatx2 ka = __builtin_amdgcn_cvt_pk_f32_fp8((int)ku, false);
        floatx2 kb = __builtin_amdgcn_cvt_pk_f32_fp8((int)ku, true);
        float p = q0 * ka.x + q1 * ka.y + q2 * kb.x + q3 * kb.y;
        p += __shfl_xor(p, 1, 64);
        p += __shfl_xor(p, 2, 64);
        p += __shfl_xor(p, 4, 64);
        p += __shfl_xor(p, 8, 64);
        float logit = p * 0.125f;  // 1/sqrt(64)
        float nm = fmaxf(m, logit);
        float f  = __expf(m - nm);
        float pe = __expf(logit - nm);
        floatx2 va = __builtin_amdgcn_cvt_pk_f32_fp8((int)vu, false);
        floatx2 vb = __builtin_amdgcn_cvt_pk_f32_fp8((int)vu, true);
        l = l * f + pe;
        a0 = a0 * f + pe * va.x;
        a1 = a1 * f + pe * va.y;
        a2 = a2 * f + pe * vb.x;
        a3 = a3 * f + pe * vb.y;
        m = nm;
        ku = kn; vu = vn;
    }

    // merge 4 partial states
    __shared__ float sm_m[4][4], sm_l[4][4];
    __shared__ float sacc[4][64][4];
    if ((lane & 15) == 0) { sm_m[g][h] = m; sm_l[g][h] = l; }
    sacc[g][lane][0] = a0; sacc[g][lane][1] = a1;
    sacc[g][lane][2] = a2; sacc[g][lane][3] = a3;
    __syncthreads();
    if (g == 0) {
        float mstar = fmaxf(fmaxf(sm_m[0][h], sm_m[1][h]), fmaxf(sm_m[2][h], sm_m[3][h]));
        float lstar = 0.f, c0 = 0.f, c1 = 0.f, c2 = 0.f, c3 = 0.f;
        #pragma unroll
        for (int gg = 0; gg < 4; gg++) {
            float lg = sm_l[gg][h];
            float sc = (lg > 0.f) ? __expf(sm_m[gg][h] - mstar) : 0.f;
            lstar += lg * sc;
            c0 += sc * sacc[gg][lane][0];
            c1 += sc * sacc[gg][lane][1];
            c2 += sc * sacc[gg][lane][2];
            c3 += sc * sacc[gg][lane][3];
        }
        float inv = (lstar > 0.f) ? 1.f / lstar : 0.f;
        size_t o = (size_t)n * 256 + off;
        uint2 sku = *(const uint2*)(skip + o);
        bf16_t r[4];
        r[0] = (bf16_t)fmaxf(bf_lo(sku.x) + c0 * inv, 0.f);
        r[1] = (bf16_t)fmaxf(bf_hi(sku.x) + c1 * inv, 0.f);
        r[2] = (bf16_t)fmaxf(bf_lo(sku.y) + c2 * inv, 0.f);
        r[3] = (bf16_t)fmaxf(bf_hi(sku.y) + c3 * inv, 0.f);
        *(uint2*)(hout + o) = *(uint2*)r;
    }
}

// ---- attention layer 2 (heads=1, d=128): ONE BLOCK (4 waves) PER NODE, fp8 k/v ----
__global__ void attn2_kernel(const bf16_t* __restrict__ q, const u8* __restrict__ kf,
                             const u8* __restrict__ vf, const int* __restrict__ row_ptr,
                             const int* __restrict__ esrc, float* __restrict__ h2) {
    int n = blockIdx.x;
    int t = threadIdx.x;
    int g = t >> 6;
    int lane = t & 63;
    int off = lane * 2;

    int beg = row_ptr[n], end = row_ptr[n + 1];

    unsigned qu = *(const unsigned*)(q + (size_t)n * 128 + off);
    float q0 = bf_lo(qu), q1 = bf_hi(qu);

    float m = -INFINITY, l = 0.f, a0 = 0.f, a1 = 0.f;

    int i0 = beg + g;
    int s_cur = (i0 < end) ? esrc[i0] : 0;
    unsigned short ku = (i0 < end) ? *(const unsigned short*)(kf + (size_t)s_cur * 128 + off) : (unsigned short)0;
    unsigned short vu = (i0 < end) ? *(const unsigned short*)(vf + (size_t)s_cur * 128 + off) : (unsigned short)0;

    for (int i = i0; i < end; i += 4) {
        int s_nxt = (i + 4 < end) ? esrc[i + 4] : 0;
        unsigned short kn = *(const unsigned short*)(kf + (size_t)s_nxt * 128 + off);
        unsigned short vn = *(const unsigned short*)(vf + (size_t)s_nxt * 128 + off);

        floatx2 kk = __builtin_amdgcn_cvt_pk_f32_fp8((int)(unsigned)ku, false);
        float p = q0 * kk.x + q1 * kk.y;
        #pragma unroll
        for (int o = 32; o; o >>= 1) p += __shfl_xor(p, o, 64);
        float logit = p * 0.08838834764831845f;  // 1/sqrt(128)
        float nm = fmaxf(m, logit);
        float f  = __expf(m - nm);
        float pe = __expf(logit - nm);
        floatx2 vv = __builtin_amdgcn_cvt_pk_f32_fp8((int)(unsigned)vu, false);
        l  = l * f + pe;
        a0 = a0 * f + pe * vv.x;
        a1 = a1 * f + pe * vv.y;
        m = nm;
        ku = kn; vu = vn;
    }

    __shared__ float sm_m[4], sm_l[4];
    __shared__ float sacc[4][64][2];
    if (lane == 0) { sm_m[g] = m; sm_l[g] = l; }
    sacc[g][lane][0] = a0; sacc[g][lane][1] = a1;
    __syncthreads();
    if (g == 0) {
        float mstar = fmaxf(fmaxf(sm_m[0], sm_m[1]), fmaxf(sm_m[2], sm_m[3]));
        float lstar = 0.f, c0 = 0.f, c1 = 0.f;
        #pragma unroll
        for (int gg = 0; gg < 4; gg++) {
            float lg = sm_l[gg];
            float sc = (lg > 0.f) ? __expf(sm_m[gg] - mstar) : 0.f;
            lstar += lg * sc;
            c0 += sc * sacc[gg][lane][0];
            c1 += sc * sacc[gg][lane][1];
        }
        float inv = (lstar > 0.f) ? 1.f / lstar : 0.f;
        float2* p2 = (float2*)(h2 + (size_t)n * 128 + off);
        float2 cur = *p2;
        cur.x += c0 * inv;
        cur.y += c1 * inv;
        *p2 = cur;
    }
}

// ---------------- final column mean over nodes ----------------
__global__ void colmean_kernel(const float* __restrict__ h2, float* __restrict__ out) {
    int t = threadIdx.x;   // 256
    int c = t & 127;
    int half = t >> 7;
    float s = 0.f;
    for (int n = blockIdx.x * 2 + half; n < NNODES; n += gridDim.x * 2)
        s += h2[(size_t)n * 128 + c];
    __shared__ float red[256];
    red[t] = s;
    __syncthreads();
    if (half == 0) {
        float tot = red[c] + red[c + 128];
        atomicAdd(&out[c], tot * (1.0f / NNODES));
    }
}

extern "C" void kernel_launch(void* const* d_in, const int* in_sizes, int n_in,
                              void* d_out, int out_size, void* d_ws, size_t ws_size,
                              hipStream_t stream) {
    const float* x  = (const float*)d_in[0];
    const int*   ei = (const int*)d_in[1];   // int32: [2, E]
    const int* src = ei;
    const int* dst = ei + NEDGES;

    const float* Wq1 = (const float*)d_in[2];  const float* bq1 = (const float*)d_in[3];
    const float* Wk1 = (const float*)d_in[4];  const float* bk1 = (const float*)d_in[5];
    const float* Wv1 = (const float*)d_in[6];  const float* bv1 = (const float*)d_in[7];
    const float* Ws1 = (const float*)d_in[8];  const float* bs1 = (const float*)d_in[9];
    const float* Wq2 = (const float*)d_in[10]; const float* bq2 = (const float*)d_in[11];
    const float* Wk2 = (const float*)d_in[12]; const float* bk2 = (const float*)d_in[13];
    const float* Wv2 = (const float*)d_in[14]; const float* bv2 = (const float*)d_in[15];
    const float* Ws2 = (const float*)d_in[16]; const float* bs2 = (const float*)d_in[17];

    float* out = (float*)d_out;

    // ---- workspace layout (byte offsets) ----
    char* ws = (char*)d_ws;
    bf16_t* q1    = (bf16_t*)(ws);                 // N*256 bf16  = 25,600,000
    u8*     k1    = (u8*)(ws + 25600000);          // N*256 fp8   = 12,800,000
    u8*     v1    = (u8*)(ws + 38400000);          // N*256 fp8   = 12,800,000
    bf16_t* hskip = (bf16_t*)(ws + 51200000);      // N*256 bf16  = 25,600,000
    bf16_t* hbf   = (bf16_t*)(ws + 76800000);      // MPAD*256 bf16 = 25,624,576
    bf16_t* xbf   = (bf16_t*)(ws + 102424576);     // MPAD*128 bf16 = 12,812,288
    bf16_t* wt1   = (bf16_t*)(ws + 115236864);     // 262,144
    bf16_t* wt2   = (bf16_t*)(ws + 115499008);     // 262,144
    int* deg     = (int*)(ws + 115761152);         // N
    int* row_ptr = deg + NNODES;                   // N+1
    int* cursor  = row_ptr + NNODES + 1;           // N
    int* esrc    = cursor + NNODES;                // E (ends ~119.6 MB)
    // layer-2 buffers alias dead layer-1 regions (stream-ordered lifetimes)
    bf16_t* q2 = (bf16_t*)(ws);                    // N*128 bf16 = 12,800,000 (over q1)
    u8*     k2 = (u8*)(ws + 12800000);             // N*128 fp8  =  6,400,000 (over q1 tail)
    u8*     v2 = (u8*)(ws + 19200000);             // N*128 fp8  =  6,400,000 (over q1 tail)
    float*  h2 = (float*)(ws + 25600000);          // N*128 f32  = 25,600,000 (over k1/v1)

    hipMemsetAsync(deg, 0, sizeof(int) * NNODES, stream);
    hipMemsetAsync(cursor, 0, sizeof(int) * NNODES, stream);
    hipMemsetAsync(out, 0, sizeof(float) * 128, stream);
    hipMemsetAsync(hbf + (size_t)NNODES * 256, 0, (size_t)(MPAD - NNODES) * 256 * sizeof(bf16_t), stream);

    // prep (cast + transposes fused)
    W4 w1; w1.W[0] = Wq1; w1.W[1] = Wk1; w1.W[2] = Wv1; w1.W[3] = Ws1;
    W4 w2; w2.W[0] = Wq2; w2.W[1] = Wk2; w2.W[2] = Wv2; w2.W[3] = Ws2;
    prep_kernel<<<(MPAD * 128 + 2 * 131072 + 255) / 256, 256, 0, stream>>>(x, w1, w2, xbf, wt1, wt2);

    // CSR
    int blocksE = (NEDGES + 255) / 256;
    count_deg_kernel<<<blocksE, 256, 0, stream>>>(dst, deg);
    scan_kernel<<<1, 1024, 0, stream>>>(deg, row_ptr);
    scatter_kernel<<<blocksE, 256, 0, stream>>>(src, dst, row_ptr, cursor, esrc);

    // layer 1
    GemmOut a1;
    a1.bias[0] = bq1; a1.bias[1] = bk1; a1.bias[2] = bv1; a1.bias[3] = bs1;
    a1.out[0] = q1;   a1.out[1] = k1;   a1.out[2] = v1;   a1.out[3] = hskip;
    a1.mode[0] = 1;   a1.mode[1] = 2;   a1.mode[2] = 2;   a1.mode[3] = 1;
    dim3 g1(MPAD / 128, 1024 / 128);   // 391 x 8
    gemm_mfma_kernel<128, 256><<<g1, 256, 0, stream>>>(xbf, wt1, a1);

    attn1_kernel<<<NNODES, 256, 0, stream>>>(q1, k1, v1, hskip, row_ptr, esrc, hbf);

    // layer 2
    GemmOut a2;
    a2.bias[0] = bq2; a2.bias[1] = bk2; a2.bias[2] = bv2; a2.bias[3] = bs2;
    a2.out[0] = q2;   a2.out[1] = k2;   a2.out[2] = v2;   a2.out[3] = h2;
    a2.mode[0] = 1;   a2.mode[1] = 2;   a2.mode[2] = 2;   a2.mode[3] = 0;
    dim3 g2(MPAD / 128, 512 / 128);    // 391 x 4
    gemm_mfma_kernel<256, 128><<<g2, 256, 0, stream>>>(hbf, wt2, a2);

    attn2_kernel<<<NNODES, 256, 0, stream>>>(q2, k2, v2, row_ptr, esrc, h2);

    colmean_kernel<<<256, 256, 0, stream>>>(h2, out);
}